// Round 1
// baseline (273.180 us; speedup 1.0000x reference)
//
#include <hip/hip_runtime.h>

// CapsuleLayer fused pipeline, round 8.
//  - R7 counters: k_route2 = 117us, MfmaUtil 0, HBM 3%, VALU 37%, Occ 24.5%
//    -> latency-bound on Q/W L2 streaming (2 MB/block x 1024 blocks = 2 GB L2).
//  - k_route3: 2 b's per 512-thread block. ow/fwv phases cross-b cooperative:
//    each Q/W float4 loaded once, FMA'd against BOTH b's xc -> L2 traffic
//    halved (1 GB). Unpadded XOR-swizzled tiles (lidx64) + cS/owS aliasing
//    -> 40 KB/b, 80 KB/block => 2 blocks/CU = 16 waves/CU (2x occupancy).
//    Grid 512 = exactly 2 x 256 CUs, single full round.
//  - k_prep2 / k_ih / k_attn unchanged (known-good).
//  - NO cooperative launches (R6 lesson: harness graph capture fails).

#define EPS_SQ 1e-7f

typedef __attribute__((ext_vector_type(8))) short bf16x8;
typedef __attribute__((ext_vector_type(4))) float floatx4;

__device__ __forceinline__ int lidx(int r, int c) {
  // 64-col fp32 tile, row stride 68 dwords, quad-swizzle (legacy kernels)
  return r * 68 + ((((c >> 2) ^ (r >> 2)) & 15) << 2) + (c & 3);
}
__device__ __forceinline__ int lidx64(int r, int c) {
  // unpadded 64-col fp32 tile, XOR swizzle at float4 granularity
  return r * 64 + ((((c >> 2) ^ r) & 15) << 2) + (c & 3);
}
__device__ __forceinline__ unsigned short f2bf(float f) {
  unsigned u = __float_as_uint(f);
  u += 0x7FFFu + ((u >> 16) & 1u);   // RNE
  return (unsigned short)(u >> 16);
}

// ---------------------------------------------------------------------------
// k_prep2: bid<32: Q_n = M_n.M_n^T ; bid 32..39: A_h = Wq_h.Wk_h^T ;
//          bid 40: symmetric pair matrix K from kmf.  (unchanged)
// ---------------------------------------------------------------------------
__global__ __launch_bounds__(256) void k_prep2(
    const float* __restrict__ W, const float* __restrict__ Wq,
    const float* __restrict__ Wk, const float* __restrict__ kmf,
    float* __restrict__ Qb, float* __restrict__ Ab, float* __restrict__ Kb)
{
  const int t = threadIdx.x;
  if (blockIdx.x < 32) {
    __shared__ __align__(16) float Mn[64 * 68];
    const int n = blockIdx.x;
#pragma unroll
    for (int k = 0; k < 4; k++) {
      int lin = t + 256 * k; int d = lin >> 4; int c0 = (lin & 15) << 2;
      *(float4*)&Mn[lidx(d, c0)] = *(const float4*)(W + d * 2048 + n * 64 + c0);
    }
    __syncthreads();
    const int d1 = (t >> 4) * 4, d2 = (t & 15) * 4;
    float acc[4][4] = {};
    for (int cq = 0; cq < 64; cq += 4) {
      float m1[4][4], m2[4][4];
#pragma unroll
      for (int i = 0; i < 4; i++) *(float4*)m1[i] = *(const float4*)&Mn[lidx(d1 + i, cq)];
#pragma unroll
      for (int j = 0; j < 4; j++) *(float4*)m2[j] = *(const float4*)&Mn[lidx(d2 + j, cq)];
#pragma unroll
      for (int i = 0; i < 4; i++)
#pragma unroll
        for (int j = 0; j < 4; j++) {
          float s = 0.f;
#pragma unroll
          for (int k = 0; k < 4; k++) s += m1[i][k] * m2[j][k];
          acc[i][j] += s;
        }
    }
#pragma unroll
    for (int i = 0; i < 4; i++)
      *(float4*)(Qb + n * 4096 + (d1 + i) * 64 + d2) = *(float4*)acc[i];
  } else if (blockIdx.x < 40) {
    __shared__ __align__(16) float wkS[64 * 68];
    __shared__ __align__(16) float wqS[16 * 68];
    const int hb = blockIdx.x - 32;
    const int h = hb & 1, rg = hb >> 1;
#pragma unroll
    for (int k = 0; k < 4; k++) {
      int lin = t + 256 * k; int dp = lin >> 4; int e0 = (lin & 15) << 2;
      *(float4*)&wkS[lidx(dp, e0)] = *(const float4*)(Wk + dp * 128 + h * 64 + e0);
    }
    {
      int dl = t >> 4, e0 = (t & 15) << 2;
      *(float4*)&wqS[lidx(dl, e0)] = *(const float4*)(Wq + (rg * 16 + dl) * 128 + h * 64 + e0);
    }
    __syncthreads();
    const int dl = t >> 4, dp0 = (t & 15) << 2;
    float acc[4] = {};
    for (int e = 0; e < 64; e += 4) {
      float q4[4];
      *(float4*)q4 = *(const float4*)&wqS[lidx(dl, e)];
#pragma unroll
      for (int c = 0; c < 4; c++) {
        float mr[4];
        *(float4*)mr = *(const float4*)&wkS[lidx(dp0 + c, e)];
        acc[c] += q4[0] * mr[0] + q4[1] * mr[1] + q4[2] * mr[2] + q4[3] * mr[3];
      }
    }
    *(float4*)(Ab + h * 4096 + (rg * 16 + dl) * 64 + dp0) = *(float4*)acc;
  } else {
    __shared__ float Ks[1024];
    *(float4*)&Ks[t * 4] = make_float4(0.f, 0.f, 0.f, 0.f);
    __syncthreads();
    if (t < 248) {
#pragma unroll
      for (int j = 0; j < 2; j++) {
        int p = t * 2 + j;
        if (p < 496) {
          int l = 0, rem = p;
          while (rem >= 31 - l) { rem -= 31 - l; ++l; }
          int r = l + 1 + rem;
          float v = kmf[p];
          Ks[l * 32 + r] = v;
          Ks[r * 32 + l] = v;
        }
      }
    }
    __syncthreads();
    *(float4*)&Kb[t * 4] = *(const float4*)&Ks[t * 4];
  }
}

// ---------------------------------------------------------------------------
// k_route3: routing for TWO b's per 512-thread block.
//   Per-b phases (softmax, xc, delta-b): lower 4 waves = b0, upper = b1.
//   Cross-b phases (ow: xc.Q with Q streamed; fwv: xc.W): every thread
//   loads each Q/W float4 once and uses it for both b's.
//   LDS per b: xs 16K | bS 8K | cOw 8K (cS aliased with owS) | xcS 8K
//   = 40 KB; 80 KB/block -> 2 blocks/CU.
// ---------------------------------------------------------------------------
__global__ __launch_bounds__(512, 4) void k_route3(
    const float* __restrict__ x, const float* __restrict__ W,
    const float* __restrict__ rinit, const float* __restrict__ Qb,
    float* __restrict__ rs, float* __restrict__ fwv)
{
  __shared__ __align__(16) float smem[2 * 10240];   // 81920 B exactly

  const int t = threadIdx.x;
  const int tb = t >> 8, tt = t & 255;
  const int b = blockIdx.x * 2 + tb;

  float* xs  = smem + tb * 10240;          // 64x64 (swizzled)
  float* bS  = smem + tb * 10240 + 4096;   // 32x64 logits (persistent)
  float* cOw = smem + tb * 10240 + 6144;   // 32x64 cS aliased with owS
  float* xcS = smem + tb * 10240 + 8192;   // 32x64

  // cross-b views for ow / fwv phases
  float* xc0 = smem + 8192;
  float* xc1 = smem + 10240 + 8192;
  float* ow0 = smem + 6144;
  float* ow1 = smem + 10240 + 6144;

  // ---- stage x[b] and rinit ----------------------------------------------
#pragma unroll
  for (int k = 0; k < 4; k++) {
    int lin = tt + 256 * k; int f = lin >> 4; int d0 = (lin & 15) << 2;
    *(float4*)&xs[lidx64(f, d0)] = *(const float4*)(x + b * 4096 + f * 64 + d0);
  }
#pragma unroll
  for (int k = 0; k < 2; k++) {
    int lin = tt + 256 * k; int n = lin >> 4; int f0 = (lin & 15) << 2;
    *(float4*)&bS[lidx64(n, f0)] = *(const float4*)(rinit + n * 64 + f0);
  }
  __syncthreads();

  const int tn = tt >> 4, tlo = tt & 15;
  const int nq = t >> 4, sub = t & 15;     // cross-b mapping: 32 n x 4 cols

  for (int it = 0; it < 4; it++) {
    // ---- cS = softmax over n per f column (per-b) -------------------------
    {
      const int nl = tt & 31, fg = tt >> 5;
#pragma unroll
      for (int k = 0; k < 8; k++) {
        int f = fg * 8 + k;
        float v = bS[lidx64(nl, f)];
        float m = v;
        for (int s = 16; s > 0; s >>= 1) m = fmaxf(m, __shfl_xor(m, s, 64));
        float e = __expf(v - m);
        float sum = e;
        for (int s = 16; s > 0; s >>= 1) sum += __shfl_xor(sum, s, 64);
        cOw[lidx64(nl, f)] = e / sum;
      }
    }
    __syncthreads();
    if (it == 3) {
#pragma unroll
      for (int k = 0; k < 8; k++) {
        int lin = tt + 256 * k; int n = lin >> 6, f = lin & 63;
        rs[b * 2048 + n * 64 + f] = cOw[lidx64(n, f)];
      }
    }
    // ---- xcS = cS . xs (per-b) -------------------------------------------
    {
      const int n0 = tn * 2, d0 = tlo * 4;
      float acc[2][4] = {{0, 0, 0, 0}, {0, 0, 0, 0}};
      for (int f = 0; f < 64; f++) {
        float c0v = cOw[lidx64(n0, f)];
        float c1v = cOw[lidx64(n0 + 1, f)];
        float xr[4];
        *(float4*)xr = *(const float4*)&xs[lidx64(f, d0)];
#pragma unroll
        for (int i = 0; i < 4; i++) {
          acc[0][i] += c0v * xr[i];
          acc[1][i] += c1v * xr[i];
        }
      }
      *(float4*)&xcS[lidx64(n0, d0)] = *(float4*)acc[0];
      *(float4*)&xcS[lidx64(n0 + 1, d0)] = *(float4*)acc[1];
    }
    __syncthreads();
    if (it == 3) break;

    // ---- ow = scale * (xc . Q_n): CROSS-B, Q streamed once ----------------
    {
      const float* Qn = Qb + nq * 4096 + sub * 4;
      float y0[4] = {}, y1[4] = {};
#pragma unroll 4
      for (int d1 = 0; d1 < 64; d1++) {
        float xv0 = xc0[lidx64(nq, d1)];
        float xv1 = xc1[lidx64(nq, d1)];
        float4 q = *(const float4*)(Qn + d1 * 64);
        y0[0] += xv0 * q.x; y0[1] += xv0 * q.y; y0[2] += xv0 * q.z; y0[3] += xv0 * q.w;
        y1[0] += xv1 * q.x; y1[1] += xv1 * q.y; y1[2] += xv1 * q.z; y1[3] += xv1 * q.w;
      }
      float xa0[4], xa1[4];
      *(float4*)xa0 = *(const float4*)&xc0[lidx64(nq, sub * 4)];
      *(float4*)xa1 = *(const float4*)&xc1[lidx64(nq, sub * 4)];
      float ps0 = y0[0] * xa0[0] + y0[1] * xa0[1] + y0[2] * xa0[2] + y0[3] * xa0[3];
      float ps1 = y1[0] * xa1[0] + y1[1] * xa1[1] + y1[2] * xa1[2] + y1[3] * xa1[3];
      ps0 += __shfl_xor(ps0, 1, 64); ps0 += __shfl_xor(ps0, 2, 64);
      ps0 += __shfl_xor(ps0, 4, 64); ps0 += __shfl_xor(ps0, 8, 64);
      ps1 += __shfl_xor(ps1, 1, 64); ps1 += __shfl_xor(ps1, 2, 64);
      ps1 += __shfl_xor(ps1, 4, 64); ps1 += __shfl_xor(ps1, 8, 64);
      const float ss0 = ps0 + EPS_SQ, ss1 = ps1 + EPS_SQ;
      const float sc0 = sqrtf(ss0) / (0.5f + ss0);
      const float sc1 = sqrtf(ss1) / (0.5f + ss1);
      float o0[4] = {y0[0] * sc0, y0[1] * sc0, y0[2] * sc0, y0[3] * sc0};
      float o1[4] = {y1[0] * sc1, y1[1] * sc1, y1[2] * sc1, y1[3] * sc1};
      *(float4*)&ow0[lidx64(nq, sub * 4)] = *(float4*)o0;
      *(float4*)&ow1[lidx64(nq, sub * 4)] = *(float4*)o1;
    }
    __syncthreads();

    // ---- bS += xs . owS^T (per-b) ----------------------------------------
    {
      const int n0 = tn * 2, f0 = tlo * 4;
      float acc[2][4] = {{0, 0, 0, 0}, {0, 0, 0, 0}};
      for (int dq = 0; dq < 64; dq += 4) {
        float o[2][4];
        *(float4*)o[0] = *(const float4*)&cOw[lidx64(n0, dq)];
        *(float4*)o[1] = *(const float4*)&cOw[lidx64(n0 + 1, dq)];
#pragma unroll
        for (int i = 0; i < 4; i++) {
          float xr[4];
          *(float4*)xr = *(const float4*)&xs[lidx64(f0 + i, dq)];
#pragma unroll
          for (int k = 0; k < 4; k++) {
            acc[0][i] += o[0][k] * xr[k];
            acc[1][i] += o[1][k] * xr[k];
          }
        }
      }
#pragma unroll
      for (int j = 0; j < 2; j++) {
        float tmp[4];
        *(float4*)tmp = *(const float4*)&bS[lidx64(n0 + j, f0)];
#pragma unroll
        for (int i = 0; i < 4; i++) tmp[i] += acc[j][i];
        *(float4*)&bS[lidx64(n0 + j, f0)] = *(float4*)tmp;
      }
    }
    __syncthreads();
  }

  // ---- fwv = xcS . W: CROSS-B, W streamed once ----------------------------
  {
    const float* Wn = W + nq * 64 + sub * 4;
    float a0[4] = {}, a1[4] = {};
#pragma unroll 4
    for (int d = 0; d < 64; d++) {
      float xv0 = xc0[lidx64(nq, d)];
      float xv1 = xc1[lidx64(nq, d)];
      float4 w = *(const float4*)(Wn + d * 2048);
      a0[0] += xv0 * w.x; a0[1] += xv0 * w.y; a0[2] += xv0 * w.z; a0[3] += xv0 * w.w;
      a1[0] += xv1 * w.x; a1[1] += xv1 * w.y; a1[2] += xv1 * w.z; a1[3] += xv1 * w.w;
    }
    const int b0g = blockIdx.x * 2;
    *(float4*)(fwv + b0g * 2048 + nq * 64 + sub * 4) = *(float4*)a0;
    *(float4*)(fwv + (b0g + 1) * 2048 + nq * 64 + sub * 4) = *(float4*)a1;
  }
}

// ---------------------------------------------------------------------------
// k_ih: ssq via bf16 MFMA. Block = 4 b's x 8 n's, grid 1024. (unchanged)
// ---------------------------------------------------------------------------
__global__ __launch_bounds__(256) void k_ih(
    const float* __restrict__ x, const float* __restrict__ W,
    const float* __restrict__ rs, float* __restrict__ ssq)
{
  __shared__ __align__(16) unsigned short xB[4 * 64 * 64];   // 32768 B
  __shared__ __align__(16) unsigned short wB[2 * 64 * 64];   // 16384 B
  __shared__ unsigned short cF2[4 * 8 * 64];                 // 4096 B
  const int n_oct = (blockIdx.x & 3) << 3, b0 = (blockIdx.x >> 2) * 4;
  const int t = threadIdx.x, w = t >> 6, lane = t & 63;

#pragma unroll
  for (int k = 0; k < 16; k++) {
    int ch = t + 256 * k;
    int bb = ch >> 10, rem = ch & 1023;
    int f = rem >> 4, fq = rem & 15;
    int dg = fq >> 1, half = fq & 1;
    float4 v = *(const float4*)(x + ((b0 + bb) * 64 + f) * 64 + fq * 4);
    unsigned p0 = f2bf(v.x) | ((unsigned)f2bf(v.y) << 16);
    unsigned p1 = f2bf(v.z) | ((unsigned)f2bf(v.w) << 16);
    *(uint2*)&xB[bb * 4096 + f * 64 + ((dg ^ (f & 7)) << 3) + half * 4] =
        make_uint2(p0, p1);
  }
#pragma unroll
  for (int nn = 0; nn < 8; nn++) {
    float v = rs[(b0 + w) * 2048 + (n_oct + nn) * 64 + lane];
    cF2[(w * 8 + nn) * 64 + lane] = f2bf(v * v);
  }
  __syncthreads();

  const int m = lane & 15, q = lane >> 4, ms = m & 7;
  bf16x8 a[4][2];
#pragma unroll
  for (int mi = 0; mi < 4; mi++) {
    const unsigned short* bp = xB + w * 4096 + (mi * 16 + m) * 64;
#pragma unroll
    for (int kk = 0; kk < 2; kk++)
      a[mi][kk] = *(const bf16x8*)&bp[((kk * 4 + q) ^ ms) << 3];
  }

  for (int np = 0; np < 4; np++) {
    const int n0 = n_oct + np * 2;
    __syncthreads();
    {
      int dd = t >> 2, cq = t & 3;
      int dg = dd >> 3, dl = dd & 7;
#pragma unroll
      for (int nn = 0; nn < 2; nn++) {
        const float* wp = W + dd * 2048 + (n0 + nn) * 64 + cq * 16;
        unsigned short* base = wB + nn * 4096;
#pragma unroll
        for (int i4 = 0; i4 < 4; i4++) {
          float4 v = *(const float4*)(wp + i4 * 4);
          float vv[4] = {v.x, v.y, v.z, v.w};
#pragma unroll
          for (int j = 0; j < 4; j++) {
            int c = cq * 16 + i4 * 4 + j;
            base[c * 64 + ((dg ^ (c & 7)) << 3) + dl] = f2bf(vv[j]);
          }
        }
      }
    }
    __syncthreads();
#pragma unroll
    for (int nn = 0; nn < 2; nn++) {
      bf16x8 bf[4][2];
#pragma unroll
      for (int ci = 0; ci < 4; ci++) {
        const unsigned short* bp = wB + nn * 4096 + (ci * 16 + m) * 64;
#pragma unroll
        for (int kk = 0; kk < 2; kk++)
          bf[ci][kk] = *(const bf16x8*)&bp[((kk * 4 + q) ^ ms) << 3];
      }
      float ps[4] = {0.f, 0.f, 0.f, 0.f};
      const unsigned short* cf = cF2 + (w * 8 + np * 2 + nn) * 64 + q * 4;
#pragma unroll
      for (int mi = 0; mi < 4; mi++) {
        float cfv[4];
#pragma unroll
        for (int r = 0; r < 4; r++)
          cfv[r] = __uint_as_float((unsigned)cf[mi * 16 + r] << 16);
#pragma unroll
        for (int ci = 0; ci < 4; ci++) {
          floatx4 c0 = {0.f, 0.f, 0.f, 0.f};
          c0 = __builtin_amdgcn_mfma_f32_16x16x32_bf16(a[mi][0], bf[ci][0], c0, 0, 0, 0);
          c0 = __builtin_amdgcn_mfma_f32_16x16x32_bf16(a[mi][1], bf[ci][1], c0, 0, 0, 0);
#pragma unroll
          for (int r = 0; r < 4; r++) { float tv = c0[r]; ps[ci] += cfv[r] * tv * tv; }
        }
      }
#pragma unroll
      for (int ci = 0; ci < 4; ci++) {
        ps[ci] += __shfl_xor(ps[ci], 16, 64);
        ps[ci] += __shfl_xor(ps[ci], 32, 64);
      }
      if (q == 0) {
#pragma unroll
        for (int ci = 0; ci < 4; ci++)
          ssq[(b0 + w) * 2048 + (n0 + nn) * 64 + ci * 16 + m] = ps[ci];
      }
    }
  }
}

// ---------------------------------------------------------------------------
// k_attn: per-b fused attention + FM + MF + high_int. (unchanged)
// ---------------------------------------------------------------------------
__global__ __launch_bounds__(256) void k_attn(
    const float* __restrict__ fwv, const float* __restrict__ ssq,
    const float* __restrict__ Ab, const float* __restrict__ Kb,
    const float* __restrict__ Wv, const float* __restrict__ Wr,
    const float* __restrict__ kfm, const float* __restrict__ bfm,
    const float* __restrict__ bmf, const float* __restrict__ khi,
    const float* __restrict__ bhi, float* __restrict__ out0)
{
  __shared__ __align__(16) float smem[8832];   // 35328 B
  float* fwS  = smem;               // 32x68 (2176 f)
  float* pS   = smem + 2176;        // 64x36 (2304 f)
  float* bufA = smem + 4480;        // 32x68 (2176 f)
  float* tS   = smem + 6656;        // 32x68 (2176 f)
  float* vS   = smem + 4480;        // 32x132 (4224 f) (alias)
  float* redH = smem + 2176;        // 16x132 (alias of pS)
  float* Kf   = smem + 4480;        // 32x32 (alias, post-vS)
  float* red1 = smem + 5504;        // 8x68

  const int b = blockIdx.x, t = threadIdx.x;
  const int tn = t >> 4, te = t & 15;
  const int n0 = tn * 2, e0 = te * 8, d0 = te * 4;

#pragma unroll
  for (int k = 0; k < 2; k++) {
    int lin = t + 256 * k; int nn = lin >> 4; int c0 = (lin & 15) << 2;
    *(float4*)&fwS[lidx(nn, c0)] = *(const float4*)(fwv + b * 2048 + nn * 64 + c0);
  }
  __syncthreads();

  for (int h = 0; h < 2; h++) {
    float tacc[2][4] = {};
    for (int half = 0; half < 2; half++) {
#pragma unroll
      for (int k = 0; k < 2; k++) {
        int lin = t + 256 * k; int d = lin >> 4; int c0 = (lin & 15) << 2;
        *(float4*)&bufA[lidx(d, c0)] =
            *(const float4*)(Ab + h * 4096 + (half * 32 + d) * 64 + c0);
      }
      __syncthreads();
      for (int dq = 0; dq < 32; dq += 4) {
        float fw0[4], fw1[4];
        *(float4*)fw0 = *(const float4*)&fwS[lidx(n0, half * 32 + dq)];
        *(float4*)fw1 = *(const float4*)&fwS[lidx(n0 + 1, half * 32 + dq)];
#pragma unroll
        for (int j = 0; j < 4; j++) {
          float mr[4];
          *(float4*)mr = *(const float4*)&bufA[lidx(dq + j, d0)];
#pragma unroll
          for (int c = 0; c < 4; c++) {
            tacc[0][c] += fw0[j] * mr[c];
            tacc[1][c] += fw1[j] * mr[c];
          }
        }
      }
      __syncthreads();
    }
    *(float4*)&tS[lidx(n0, d0)] = *(float4*)tacc[0];
    *(float4*)&tS[lidx(n0 + 1, d0)] = *(float4*)tacc[1];
    __syncthreads();
    {
      const int m0 = te * 2;
      float s00 = 0.f, s01 = 0.f, s10 = 0.f, s11 = 0.f;
      for (int kk = 0; kk < 16; kk++) {
        float ta0[4], ta1[4], f0[4], f1[4];
        *(float4*)ta0 = *(const float4*)&tS[lidx(n0, kk * 4)];
        *(float4*)ta1 = *(const float4*)&tS[lidx(n0 + 1, kk * 4)];
        *(float4*)f0 = *(const float4*)&fwS[lidx(m0, kk * 4)];
        *(float4*)f1 = *(const float4*)&fwS[lidx(m0 + 1, kk * 4)];
#pragma unroll
        for (int j = 0; j < 4; j++) {
          s00 += ta0[j] * f0[j]; s01 += ta0[j] * f1[j];
          s10 += ta1[j] * f0[j]; s11 += ta1[j] * f1[j];
        }
      }
      pS[(h * 32 + n0) * 36 + m0] = s00;
      pS[(h * 32 + n0) * 36 + m0 + 1] = s01;
      pS[(h * 32 + n0 + 1) * 36 + m0] = s10;
      pS[(h * 32 + n0 + 1) * 36 + m0 + 1] = s11;
    }
    __syncthreads();
  }

  {
    const int r = t >> 2, sub = t & 3;
    const int base = r * 36 + sub * 8;
    float v0[4], v1[4];
    *(float4*)v0 = *(const float4*)&pS[base];
    *(float4*)v1 = *(const float4*)&pS[base + 4];
    float mx = fmaxf(fmaxf(fmaxf(v0[0], v0[1]), fmaxf(v0[2], v0[3])),
                     fmaxf(fmaxf(v1[0], v1[1]), fmaxf(v1[2], v1[3])));
    mx = fmaxf(mx, __shfl_xor(mx, 1, 64));
    mx = fmaxf(mx, __shfl_xor(mx, 2, 64));
    float sum = 0.f;
#pragma unroll
    for (int j = 0; j < 4; j++) { v0[j] = __expf(v0[j] - mx); sum += v0[j]; }
#pragma unroll
    for (int j = 0; j < 4; j++) { v1[j] = __expf(v1[j] - mx); sum += v1[j]; }
    sum += __shfl_xor(sum, 1, 64);
    sum += __shfl_xor(sum, 2, 64);
    const float inv = 1.0f / sum;
#pragma unroll
    for (int j = 0; j < 4; j++) { v0[j] *= inv; v1[j] *= inv; }
    *(float4*)&pS[base] = *(float4*)v0;
    *(float4*)&pS[base + 4] = *(float4*)v1;
  }
  __syncthreads();

  {
    float acc[2][8] = {};
    for (int dq = 0; dq < 64; dq += 4) {
      float fw0[4], fw1[4];
      *(float4*)fw0 = *(const float4*)&fwS[lidx(n0, dq)];
      *(float4*)fw1 = *(const float4*)&fwS[lidx(n0 + 1, dq)];
#pragma unroll
      for (int jj = 0; jj < 4; jj++) {
        float w8[8];
        *(float4*)&w8[0] = *(const float4*)(Wv + (dq + jj) * 128 + e0);
        *(float4*)&w8[4] = *(const float4*)(Wv + (dq + jj) * 128 + e0 + 4);
#pragma unroll
        for (int j = 0; j < 8; j++) {
          acc[0][j] += fw0[jj] * w8[j];
          acc[1][j] += fw1[jj] * w8[j];
        }
      }
    }
    *(float4*)&vS[n0 * 132 + e0] = *(float4*)&acc[0][0];
    *(float4*)&vS[n0 * 132 + e0 + 4] = *(float4*)&acc[0][4];
    *(float4*)&vS[(n0 + 1) * 132 + e0] = *(float4*)&acc[1][0];
    *(float4*)&vS[(n0 + 1) * 132 + e0 + 4] = *(float4*)&acc[1][4];
  }
  __syncthreads();

  {
    const int h2 = te >> 3;
    float pacc[2][8] = {};
    for (int m = 0; m < 32; m++) {
      float p0 = pS[(h2 * 32 + n0) * 36 + m];
      float p1 = pS[(h2 * 32 + n0 + 1) * 36 + m];
      float vr[8];
      *(float4*)&vr[0] = *(const float4*)&vS[m * 132 + e0];
      *(float4*)&vr[4] = *(const float4*)&vS[m * 132 + e0 + 4];
#pragma unroll
      for (int j = 0; j < 8; j++) {
        pacc[0][j] += p0 * vr[j];
        pacc[1][j] += p1 * vr[j];
      }
    }
    for (int dq = 0; dq < 64; dq += 4) {
      float fw0[4], fw1[4];
      *(float4*)fw0 = *(const float4*)&fwS[lidx(n0, dq)];
      *(float4*)fw1 = *(const float4*)&fwS[lidx(n0 + 1, dq)];
#pragma unroll
      for (int jj = 0; jj < 4; jj++) {
        float w8[8];
        *(float4*)&w8[0] = *(const float4*)(Wr + (dq + jj) * 128 + e0);
        *(float4*)&w8[4] = *(const float4*)(Wr + (dq + jj) * 128 + e0 + 4);
#pragma unroll
        for (int j = 0; j < 8; j++) {
          pacc[0][j] += fw0[jj] * w8[j];
          pacc[1][j] += fw1[jj] * w8[j];
        }
      }
    }
    __syncthreads();
    {
      float kh0 = khi[n0], kh1 = khi[n0 + 1];
      float ph[8];
#pragma unroll
      for (int j = 0; j < 8; j++)
        ph[j] = kh0 * fmaxf(pacc[0][j], 0.f) + kh1 * fmaxf(pacc[1][j], 0.f);
      *(float4*)&redH[tn * 132 + e0] = *(float4*)&ph[0];
      *(float4*)&redH[tn * 132 + e0 + 4] = *(float4*)&ph[4];
    }
  }
  *(float4*)&Kf[t * 4] = *(const float4*)(Kb + t * 4);
  __syncthreads();

  if (t < 128) {
    float s = 0.f;
#pragma unroll
    for (int k = 0; k < 16; k++) s += redH[k * 132 + t];
    out0[b * 256 + 128 + t] = s + bhi[t];
  }
  {
    const int c = t & 63, nq = t >> 6;
    float p = 0.f;
#pragma unroll
    for (int k = 0; k < 8; k++) {
      int nn = nq * 8 + k;
      float fv = fwS[lidx(nn, c)];
      float sv = ssq[b * 2048 + nn * 64 + c];
      p += (fv * fv - sv) * kfm[nn];
    }
    red1[nq * 68 + c] = p;
    float inner[8] = {};
    for (int r = 0; r < 32; r++) {
      float fr = fwS[lidx(r, c)];
#pragma unroll
      for (int l8 = 0; l8 < 8; l8++)
        inner[l8] += Kf[(nq * 8 + l8) * 32 + r] * fr;
    }
    float hmf = 0.f;
#pragma unroll
    for (int l8 = 0; l8 < 8; l8++)
      hmf += fwS[lidx(nq * 8 + l8, c)] * inner[l8];
    red1[(4 + nq) * 68 + c] = hmf;
  }
  __syncthreads();
  if (t < 64) {
    out0[b * 256 + t] = red1[t] + red1[68 + t] + red1[136 + t] + red1[204 + t] + bfm[t];
    float h2 = red1[272 + t] + red1[340 + t] + red1[408 + t] + red1[476 + t];
    out0[b * 256 + 64 + t] = 0.5f * h2 + bmf[t];
  }
}

// ---------------------------------------------------------------------------
extern "C" void kernel_launch(void* const* d_in, const int* in_sizes, int n_in,
                              void* d_out, int out_size, void* d_ws, size_t ws_size,
                              hipStream_t stream) {
  (void)in_sizes; (void)n_in; (void)out_size; (void)ws_size;
  const float* x     = (const float*)d_in[0];
  const float* W     = (const float*)d_in[1];
  const float* rinit = (const float*)d_in[2];
  const float* kfm   = (const float*)d_in[3];
  const float* bfm   = (const float*)d_in[4];
  const float* kmf   = (const float*)d_in[5];
  const float* bmf   = (const float*)d_in[6];
  const float* khi   = (const float*)d_in[7];
  const float* bhi   = (const float*)d_in[8];
  const float* Wq    = (const float*)d_in[9];
  const float* Wk    = (const float*)d_in[10];
  const float* Wv    = (const float*)d_in[11];
  const float* Wr    = (const float*)d_in[12];

  float* out0 = (float*)d_out;
  float* rs   = out0 + 1024 * 256;  // routing_score [B,32,64,1]

  float* ws   = (float*)d_ws;       // 24 MB
  float* Abuf = ws;                 // [2][64][64] = 8192 f
  float* Kbuf = ws + 8192;          // [32][32]    = 1024 f
  float* Qbuf = ws + 16384;         // [32][64][64] = 131072 f
  float* fwv  = ws + 2097152;       // [B,32,64]
  float* ssq  = ws + 2 * 2097152;   // [B,32,64]

  k_prep2<<<41, 256, 0, stream>>>(W, Wq, Wk, kmf, Qbuf, Abuf, Kbuf);
  k_route3<<<512, 512, 0, stream>>>(x, W, rinit, Qbuf, rs, fwv);
  k_ih<<<1024, 256, 0, stream>>>(x, W, rs, ssq);
  k_attn<<<1024, 256, 0, stream>>>(fwv, ssq, Abuf, Kbuf, Wv, Wr,
                                   kfm, bfm, bmf, khi, bhi, out0);
}

// Round 2
// 262.180 us; speedup vs baseline: 1.0420x; 1.0420x over previous
//
#include <hip/hip_runtime.h>

// CapsuleLayer fused pipeline, round 9.
//  - R8 POST-MORTEM: halving L2 + doubling occupancy was NEUTRAL (117->120us).
//    SQ_LDS_BANK_CONFLICT went 917K -> 9.4M: the unpadded lidx64 tile makes the
//    softmax column read (f fixed, n varying) a 4-way bank conflict, and the
//    scalar-heavy inner loops keep the per-CU LDS pipe saturated -> extra
//    occupancy had nothing to overlap into.
//  - R9: conflict-free softmax (float4 row-segment loads + per-element shfl
//    reduction, same shuffle count) + manual float4 vectorization of ALL
//    remaining scalar LDS reads (xc: 192->96 ds ops/thread, ow/fwv: 128->32,
//    rs-write: 8->2). No precision or structural changes.
//  - k_prep2 / k_ih / k_attn unchanged (known-good).
//  - NO cooperative launches (R6 lesson: harness graph capture fails).

#define EPS_SQ 1e-7f

typedef __attribute__((ext_vector_type(8))) short bf16x8;
typedef __attribute__((ext_vector_type(4))) float floatx4;

__device__ __forceinline__ int lidx(int r, int c) {
  // 64-col fp32 tile, row stride 68 dwords, quad-swizzle (legacy kernels)
  return r * 68 + ((((c >> 2) ^ (r >> 2)) & 15) << 2) + (c & 3);
}
__device__ __forceinline__ int lidx64(int r, int c) {
  // unpadded 64-col fp32 tile, XOR swizzle at float4 granularity
  return r * 64 + ((((c >> 2) ^ r) & 15) << 2) + (c & 3);
}
__device__ __forceinline__ unsigned short f2bf(float f) {
  unsigned u = __float_as_uint(f);
  u += 0x7FFFu + ((u >> 16) & 1u);   // RNE
  return (unsigned short)(u >> 16);
}

// ---------------------------------------------------------------------------
// k_prep2: bid<32: Q_n = M_n.M_n^T ; bid 32..39: A_h = Wq_h.Wk_h^T ;
//          bid 40: symmetric pair matrix K from kmf.  (unchanged)
// ---------------------------------------------------------------------------
__global__ __launch_bounds__(256) void k_prep2(
    const float* __restrict__ W, const float* __restrict__ Wq,
    const float* __restrict__ Wk, const float* __restrict__ kmf,
    float* __restrict__ Qb, float* __restrict__ Ab, float* __restrict__ Kb)
{
  const int t = threadIdx.x;
  if (blockIdx.x < 32) {
    __shared__ __align__(16) float Mn[64 * 68];
    const int n = blockIdx.x;
#pragma unroll
    for (int k = 0; k < 4; k++) {
      int lin = t + 256 * k; int d = lin >> 4; int c0 = (lin & 15) << 2;
      *(float4*)&Mn[lidx(d, c0)] = *(const float4*)(W + d * 2048 + n * 64 + c0);
    }
    __syncthreads();
    const int d1 = (t >> 4) * 4, d2 = (t & 15) * 4;
    float acc[4][4] = {};
    for (int cq = 0; cq < 64; cq += 4) {
      float m1[4][4], m2[4][4];
#pragma unroll
      for (int i = 0; i < 4; i++) *(float4*)m1[i] = *(const float4*)&Mn[lidx(d1 + i, cq)];
#pragma unroll
      for (int j = 0; j < 4; j++) *(float4*)m2[j] = *(const float4*)&Mn[lidx(d2 + j, cq)];
#pragma unroll
      for (int i = 0; i < 4; i++)
#pragma unroll
        for (int j = 0; j < 4; j++) {
          float s = 0.f;
#pragma unroll
          for (int k = 0; k < 4; k++) s += m1[i][k] * m2[j][k];
          acc[i][j] += s;
        }
    }
#pragma unroll
    for (int i = 0; i < 4; i++)
      *(float4*)(Qb + n * 4096 + (d1 + i) * 64 + d2) = *(float4*)acc[i];
  } else if (blockIdx.x < 40) {
    __shared__ __align__(16) float wkS[64 * 68];
    __shared__ __align__(16) float wqS[16 * 68];
    const int hb = blockIdx.x - 32;
    const int h = hb & 1, rg = hb >> 1;
#pragma unroll
    for (int k = 0; k < 4; k++) {
      int lin = t + 256 * k; int dp = lin >> 4; int e0 = (lin & 15) << 2;
      *(float4*)&wkS[lidx(dp, e0)] = *(const float4*)(Wk + dp * 128 + h * 64 + e0);
    }
    {
      int dl = t >> 4, e0 = (t & 15) << 2;
      *(float4*)&wqS[lidx(dl, e0)] = *(const float4*)(Wq + (rg * 16 + dl) * 128 + h * 64 + e0);
    }
    __syncthreads();
    const int dl = t >> 4, dp0 = (t & 15) << 2;
    float acc[4] = {};
    for (int e = 0; e < 64; e += 4) {
      float q4[4];
      *(float4*)q4 = *(const float4*)&wqS[lidx(dl, e)];
#pragma unroll
      for (int c = 0; c < 4; c++) {
        float mr[4];
        *(float4*)mr = *(const float4*)&wkS[lidx(dp0 + c, e)];
        acc[c] += q4[0] * mr[0] + q4[1] * mr[1] + q4[2] * mr[2] + q4[3] * mr[3];
      }
    }
    *(float4*)(Ab + h * 4096 + (rg * 16 + dl) * 64 + dp0) = *(float4*)acc;
  } else {
    __shared__ float Ks[1024];
    *(float4*)&Ks[t * 4] = make_float4(0.f, 0.f, 0.f, 0.f);
    __syncthreads();
    if (t < 248) {
#pragma unroll
      for (int j = 0; j < 2; j++) {
        int p = t * 2 + j;
        if (p < 496) {
          int l = 0, rem = p;
          while (rem >= 31 - l) { rem -= 31 - l; ++l; }
          int r = l + 1 + rem;
          float v = kmf[p];
          Ks[l * 32 + r] = v;
          Ks[r * 32 + l] = v;
        }
      }
    }
    __syncthreads();
    *(float4*)&Kb[t * 4] = *(const float4*)&Ks[t * 4];
  }
}

// ---------------------------------------------------------------------------
// k_route3: routing for TWO b's per 512-thread block.
//   Per-b phases (softmax, xc, delta-b): lower 4 waves = b0, upper = b1.
//   Cross-b phases (ow: xc.Q with Q streamed; fwv: xc.W): every thread
//   loads each Q/W float4 once and uses it for both b's.
//   LDS per b: xs 16K | bS 8K | cOw 8K (cS aliased with owS) | xcS 8K
//   = 40 KB; 80 KB/block -> 2 blocks/CU.
//   R9: all LDS accesses float4-vectorized; softmax conflict-free.
// ---------------------------------------------------------------------------
__global__ __launch_bounds__(512, 4) void k_route3(
    const float* __restrict__ x, const float* __restrict__ W,
    const float* __restrict__ rinit, const float* __restrict__ Qb,
    float* __restrict__ rs, float* __restrict__ fwv)
{
  __shared__ __align__(16) float smem[2 * 10240];   // 81920 B exactly

  const int t = threadIdx.x;
  const int tb = t >> 8, tt = t & 255;
  const int b = blockIdx.x * 2 + tb;

  float* xs  = smem + tb * 10240;          // 64x64 (swizzled)
  float* bS  = smem + tb * 10240 + 4096;   // 32x64 logits (persistent)
  float* cOw = smem + tb * 10240 + 6144;   // 32x64 cS aliased with owS
  float* xcS = smem + tb * 10240 + 8192;   // 32x64

  // cross-b views for ow / fwv phases
  float* xc0 = smem + 8192;
  float* xc1 = smem + 10240 + 8192;
  float* ow0 = smem + 6144;
  float* ow1 = smem + 10240 + 6144;

  // ---- stage x[b] and rinit ----------------------------------------------
#pragma unroll
  for (int k = 0; k < 4; k++) {
    int lin = tt + 256 * k; int f = lin >> 4; int d0 = (lin & 15) << 2;
    *(float4*)&xs[lidx64(f, d0)] = *(const float4*)(x + b * 4096 + f * 64 + d0);
  }
#pragma unroll
  for (int k = 0; k < 2; k++) {
    int lin = tt + 256 * k; int n = lin >> 4; int f0 = (lin & 15) << 2;
    *(float4*)&bS[lidx64(n, f0)] = *(const float4*)(rinit + n * 64 + f0);
  }
  __syncthreads();

  const int tn = tt >> 4, tlo = tt & 15;
  const int nq = t >> 4, sub = t & 15;     // cross-b mapping: 32 n x 4 cols

  for (int it = 0; it < 4; it++) {
    // ---- cS = softmax over n per f column (per-b) -------------------------
    // R9: float4 row-segment loads (conflict-free), per-element shfl reduce.
    {
      const int nl = tt & 31, fg = tt >> 5;   // fg 0..7
#pragma unroll
      for (int qq = 0; qq < 2; qq++) {
        const int f0 = (fg * 2 + qq) * 4;
        float v[4];
        *(float4*)v = *(const float4*)&bS[lidx64(nl, f0)];
        float e[4];
#pragma unroll
        for (int j = 0; j < 4; j++) {
          float m = v[j];
          m = fmaxf(m, __shfl_xor(m, 16, 64));
          m = fmaxf(m, __shfl_xor(m, 8, 64));
          m = fmaxf(m, __shfl_xor(m, 4, 64));
          m = fmaxf(m, __shfl_xor(m, 2, 64));
          m = fmaxf(m, __shfl_xor(m, 1, 64));
          e[j] = __expf(v[j] - m);
          float s = e[j];
          s += __shfl_xor(s, 16, 64);
          s += __shfl_xor(s, 8, 64);
          s += __shfl_xor(s, 4, 64);
          s += __shfl_xor(s, 2, 64);
          s += __shfl_xor(s, 1, 64);
          e[j] /= s;
        }
        *(float4*)&cOw[lidx64(nl, f0)] = *(float4*)e;
      }
    }
    __syncthreads();
    if (it == 3) {
#pragma unroll
      for (int k = 0; k < 2; k++) {
        int lin = tt + 256 * k;              // 0..511
        int n = lin >> 4, fq = lin & 15;
        float4 v = *(const float4*)&cOw[lidx64(n, fq * 4)];
        *(float4*)(rs + b * 2048 + n * 64 + fq * 4) = v;
      }
    }
    // ---- xcS = cS . xs (per-b) -------------------------------------------
    {
      const int n0 = tn * 2, d0 = tlo * 4;
      float acc[2][4] = {{0, 0, 0, 0}, {0, 0, 0, 0}};
      for (int fq = 0; fq < 16; fq++) {
        float c0[4], c1[4];
        *(float4*)c0 = *(const float4*)&cOw[lidx64(n0, fq * 4)];
        *(float4*)c1 = *(const float4*)&cOw[lidx64(n0 + 1, fq * 4)];
#pragma unroll
        for (int j = 0; j < 4; j++) {
          float xr[4];
          *(float4*)xr = *(const float4*)&xs[lidx64(fq * 4 + j, d0)];
#pragma unroll
          for (int i = 0; i < 4; i++) {
            acc[0][i] += c0[j] * xr[i];
            acc[1][i] += c1[j] * xr[i];
          }
        }
      }
      *(float4*)&xcS[lidx64(n0, d0)] = *(float4*)acc[0];
      *(float4*)&xcS[lidx64(n0 + 1, d0)] = *(float4*)acc[1];
    }
    __syncthreads();
    if (it == 3) break;

    // ---- ow = scale * (xc . Q_n): CROSS-B, Q streamed once ----------------
    {
      const float* Qn = Qb + nq * 4096 + sub * 4;
      float y0[4] = {}, y1[4] = {};
#pragma unroll 4
      for (int dq = 0; dq < 16; dq++) {
        float xv0[4], xv1[4];
        *(float4*)xv0 = *(const float4*)&xc0[lidx64(nq, dq * 4)];
        *(float4*)xv1 = *(const float4*)&xc1[lidx64(nq, dq * 4)];
#pragma unroll
        for (int j = 0; j < 4; j++) {
          float4 q = *(const float4*)(Qn + (dq * 4 + j) * 64);
          y0[0] += xv0[j] * q.x; y0[1] += xv0[j] * q.y;
          y0[2] += xv0[j] * q.z; y0[3] += xv0[j] * q.w;
          y1[0] += xv1[j] * q.x; y1[1] += xv1[j] * q.y;
          y1[2] += xv1[j] * q.z; y1[3] += xv1[j] * q.w;
        }
      }
      float xa0[4], xa1[4];
      *(float4*)xa0 = *(const float4*)&xc0[lidx64(nq, sub * 4)];
      *(float4*)xa1 = *(const float4*)&xc1[lidx64(nq, sub * 4)];
      float ps0 = y0[0] * xa0[0] + y0[1] * xa0[1] + y0[2] * xa0[2] + y0[3] * xa0[3];
      float ps1 = y1[0] * xa1[0] + y1[1] * xa1[1] + y1[2] * xa1[2] + y1[3] * xa1[3];
      ps0 += __shfl_xor(ps0, 1, 64); ps0 += __shfl_xor(ps0, 2, 64);
      ps0 += __shfl_xor(ps0, 4, 64); ps0 += __shfl_xor(ps0, 8, 64);
      ps1 += __shfl_xor(ps1, 1, 64); ps1 += __shfl_xor(ps1, 2, 64);
      ps1 += __shfl_xor(ps1, 4, 64); ps1 += __shfl_xor(ps1, 8, 64);
      const float ss0 = ps0 + EPS_SQ, ss1 = ps1 + EPS_SQ;
      const float sc0 = sqrtf(ss0) / (0.5f + ss0);
      const float sc1 = sqrtf(ss1) / (0.5f + ss1);
      float o0[4] = {y0[0] * sc0, y0[1] * sc0, y0[2] * sc0, y0[3] * sc0};
      float o1[4] = {y1[0] * sc1, y1[1] * sc1, y1[2] * sc1, y1[3] * sc1};
      *(float4*)&ow0[lidx64(nq, sub * 4)] = *(float4*)o0;
      *(float4*)&ow1[lidx64(nq, sub * 4)] = *(float4*)o1;
    }
    __syncthreads();

    // ---- bS += xs . owS^T (per-b) ----------------------------------------
    {
      const int n0 = tn * 2, f0 = tlo * 4;
      float acc[2][4] = {{0, 0, 0, 0}, {0, 0, 0, 0}};
      for (int dq = 0; dq < 64; dq += 4) {
        float o[2][4];
        *(float4*)o[0] = *(const float4*)&cOw[lidx64(n0, dq)];
        *(float4*)o[1] = *(const float4*)&cOw[lidx64(n0 + 1, dq)];
#pragma unroll
        for (int i = 0; i < 4; i++) {
          float xr[4];
          *(float4*)xr = *(const float4*)&xs[lidx64(f0 + i, dq)];
#pragma unroll
          for (int k = 0; k < 4; k++) {
            acc[0][i] += o[0][k] * xr[k];
            acc[1][i] += o[1][k] * xr[k];
          }
        }
      }
#pragma unroll
      for (int j = 0; j < 2; j++) {
        float tmp[4];
        *(float4*)tmp = *(const float4*)&bS[lidx64(n0 + j, f0)];
#pragma unroll
        for (int i = 0; i < 4; i++) tmp[i] += acc[j][i];
        *(float4*)&bS[lidx64(n0 + j, f0)] = *(float4*)tmp;
      }
    }
    __syncthreads();
  }

  // ---- fwv = xcS . W: CROSS-B, W streamed once ----------------------------
  {
    const float* Wn = W + nq * 64 + sub * 4;
    float a0[4] = {}, a1[4] = {};
#pragma unroll 4
    for (int dq = 0; dq < 16; dq++) {
      float xv0[4], xv1[4];
      *(float4*)xv0 = *(const float4*)&xc0[lidx64(nq, dq * 4)];
      *(float4*)xv1 = *(const float4*)&xc1[lidx64(nq, dq * 4)];
#pragma unroll
      for (int j = 0; j < 4; j++) {
        float4 w = *(const float4*)(Wn + (dq * 4 + j) * 2048);
        a0[0] += xv0[j] * w.x; a0[1] += xv0[j] * w.y;
        a0[2] += xv0[j] * w.z; a0[3] += xv0[j] * w.w;
        a1[0] += xv1[j] * w.x; a1[1] += xv1[j] * w.y;
        a1[2] += xv1[j] * w.z; a1[3] += xv1[j] * w.w;
      }
    }
    const int b0g = blockIdx.x * 2;
    *(float4*)(fwv + b0g * 2048 + nq * 64 + sub * 4) = *(float4*)a0;
    *(float4*)(fwv + (b0g + 1) * 2048 + nq * 64 + sub * 4) = *(float4*)a1;
  }
}

// ---------------------------------------------------------------------------
// k_ih: ssq via bf16 MFMA. Block = 4 b's x 8 n's, grid 1024. (unchanged)
// ---------------------------------------------------------------------------
__global__ __launch_bounds__(256) void k_ih(
    const float* __restrict__ x, const float* __restrict__ W,
    const float* __restrict__ rs, float* __restrict__ ssq)
{
  __shared__ __align__(16) unsigned short xB[4 * 64 * 64];   // 32768 B
  __shared__ __align__(16) unsigned short wB[2 * 64 * 64];   // 16384 B
  __shared__ unsigned short cF2[4 * 8 * 64];                 // 4096 B
  const int n_oct = (blockIdx.x & 3) << 3, b0 = (blockIdx.x >> 2) * 4;
  const int t = threadIdx.x, w = t >> 6, lane = t & 63;

#pragma unroll
  for (int k = 0; k < 16; k++) {
    int ch = t + 256 * k;
    int bb = ch >> 10, rem = ch & 1023;
    int f = rem >> 4, fq = rem & 15;
    int dg = fq >> 1, half = fq & 1;
    float4 v = *(const float4*)(x + ((b0 + bb) * 64 + f) * 64 + fq * 4);
    unsigned p0 = f2bf(v.x) | ((unsigned)f2bf(v.y) << 16);
    unsigned p1 = f2bf(v.z) | ((unsigned)f2bf(v.w) << 16);
    *(uint2*)&xB[bb * 4096 + f * 64 + ((dg ^ (f & 7)) << 3) + half * 4] =
        make_uint2(p0, p1);
  }
#pragma unroll
  for (int nn = 0; nn < 8; nn++) {
    float v = rs[(b0 + w) * 2048 + (n_oct + nn) * 64 + lane];
    cF2[(w * 8 + nn) * 64 + lane] = f2bf(v * v);
  }
  __syncthreads();

  const int m = lane & 15, q = lane >> 4, ms = m & 7;
  bf16x8 a[4][2];
#pragma unroll
  for (int mi = 0; mi < 4; mi++) {
    const unsigned short* bp = xB + w * 4096 + (mi * 16 + m) * 64;
#pragma unroll
    for (int kk = 0; kk < 2; kk++)
      a[mi][kk] = *(const bf16x8*)&bp[((kk * 4 + q) ^ ms) << 3];
  }

  for (int np = 0; np < 4; np++) {
    const int n0 = n_oct + np * 2;
    __syncthreads();
    {
      int dd = t >> 2, cq = t & 3;
      int dg = dd >> 3, dl = dd & 7;
#pragma unroll
      for (int nn = 0; nn < 2; nn++) {
        const float* wp = W + dd * 2048 + (n0 + nn) * 64 + cq * 16;
        unsigned short* base = wB + nn * 4096;
#pragma unroll
        for (int i4 = 0; i4 < 4; i4++) {
          float4 v = *(const float4*)(wp + i4 * 4);
          float vv[4] = {v.x, v.y, v.z, v.w};
#pragma unroll
          for (int j = 0; j < 4; j++) {
            int c = cq * 16 + i4 * 4 + j;
            base[c * 64 + ((dg ^ (c & 7)) << 3) + dl] = f2bf(vv[j]);
          }
        }
      }
    }
    __syncthreads();
#pragma unroll
    for (int nn = 0; nn < 2; nn++) {
      bf16x8 bf[4][2];
#pragma unroll
      for (int ci = 0; ci < 4; ci++) {
        const unsigned short* bp = wB + nn * 4096 + (ci * 16 + m) * 64;
#pragma unroll
        for (int kk = 0; kk < 2; kk++)
          bf[ci][kk] = *(const bf16x8*)&bp[((kk * 4 + q) ^ ms) << 3];
      }
      float ps[4] = {0.f, 0.f, 0.f, 0.f};
      const unsigned short* cf = cF2 + (w * 8 + np * 2 + nn) * 64 + q * 4;
#pragma unroll
      for (int mi = 0; mi < 4; mi++) {
        float cfv[4];
#pragma unroll
        for (int r = 0; r < 4; r++)
          cfv[r] = __uint_as_float((unsigned)cf[mi * 16 + r] << 16);
#pragma unroll
        for (int ci = 0; ci < 4; ci++) {
          floatx4 c0 = {0.f, 0.f, 0.f, 0.f};
          c0 = __builtin_amdgcn_mfma_f32_16x16x32_bf16(a[mi][0], bf[ci][0], c0, 0, 0, 0);
          c0 = __builtin_amdgcn_mfma_f32_16x16x32_bf16(a[mi][1], bf[ci][1], c0, 0, 0, 0);
#pragma unroll
          for (int r = 0; r < 4; r++) { float tv = c0[r]; ps[ci] += cfv[r] * tv * tv; }
        }
      }
#pragma unroll
      for (int ci = 0; ci < 4; ci++) {
        ps[ci] += __shfl_xor(ps[ci], 16, 64);
        ps[ci] += __shfl_xor(ps[ci], 32, 64);
      }
      if (q == 0) {
#pragma unroll
        for (int ci = 0; ci < 4; ci++)
          ssq[(b0 + w) * 2048 + (n0 + nn) * 64 + ci * 16 + m] = ps[ci];
      }
    }
  }
}

// ---------------------------------------------------------------------------
// k_attn: per-b fused attention + FM + MF + high_int. (unchanged)
// ---------------------------------------------------------------------------
__global__ __launch_bounds__(256) void k_attn(
    const float* __restrict__ fwv, const float* __restrict__ ssq,
    const float* __restrict__ Ab, const float* __restrict__ Kb,
    const float* __restrict__ Wv, const float* __restrict__ Wr,
    const float* __restrict__ kfm, const float* __restrict__ bfm,
    const float* __restrict__ bmf, const float* __restrict__ khi,
    const float* __restrict__ bhi, float* __restrict__ out0)
{
  __shared__ __align__(16) float smem[8832];   // 35328 B
  float* fwS  = smem;               // 32x68 (2176 f)
  float* pS   = smem + 2176;        // 64x36 (2304 f)
  float* bufA = smem + 4480;        // 32x68 (2176 f)
  float* tS   = smem + 6656;        // 32x68 (2176 f)
  float* vS   = smem + 4480;        // 32x132 (4224 f) (alias)
  float* redH = smem + 2176;        // 16x132 (alias of pS)
  float* Kf   = smem + 4480;        // 32x32 (alias, post-vS)
  float* red1 = smem + 5504;        // 8x68

  const int b = blockIdx.x, t = threadIdx.x;
  const int tn = t >> 4, te = t & 15;
  const int n0 = tn * 2, e0 = te * 8, d0 = te * 4;

#pragma unroll
  for (int k = 0; k < 2; k++) {
    int lin = t + 256 * k; int nn = lin >> 4; int c0 = (lin & 15) << 2;
    *(float4*)&fwS[lidx(nn, c0)] = *(const float4*)(fwv + b * 2048 + nn * 64 + c0);
  }
  __syncthreads();

  for (int h = 0; h < 2; h++) {
    float tacc[2][4] = {};
    for (int half = 0; half < 2; half++) {
#pragma unroll
      for (int k = 0; k < 2; k++) {
        int lin = t + 256 * k; int d = lin >> 4; int c0 = (lin & 15) << 2;
        *(float4*)&bufA[lidx(d, c0)] =
            *(const float4*)(Ab + h * 4096 + (half * 32 + d) * 64 + c0);
      }
      __syncthreads();
      for (int dq = 0; dq < 32; dq += 4) {
        float fw0[4], fw1[4];
        *(float4*)fw0 = *(const float4*)&fwS[lidx(n0, half * 32 + dq)];
        *(float4*)fw1 = *(const float4*)&fwS[lidx(n0 + 1, half * 32 + dq)];
#pragma unroll
        for (int j = 0; j < 4; j++) {
          float mr[4];
          *(float4*)mr = *(const float4*)&bufA[lidx(dq + j, d0)];
#pragma unroll
          for (int c = 0; c < 4; c++) {
            tacc[0][c] += fw0[j] * mr[c];
            tacc[1][c] += fw1[j] * mr[c];
          }
        }
      }
      __syncthreads();
    }
    *(float4*)&tS[lidx(n0, d0)] = *(float4*)tacc[0];
    *(float4*)&tS[lidx(n0 + 1, d0)] = *(float4*)tacc[1];
    __syncthreads();
    {
      const int m0 = te * 2;
      float s00 = 0.f, s01 = 0.f, s10 = 0.f, s11 = 0.f;
      for (int kk = 0; kk < 16; kk++) {
        float ta0[4], ta1[4], f0[4], f1[4];
        *(float4*)ta0 = *(const float4*)&tS[lidx(n0, kk * 4)];
        *(float4*)ta1 = *(const float4*)&tS[lidx(n0 + 1, kk * 4)];
        *(float4*)f0 = *(const float4*)&fwS[lidx(m0, kk * 4)];
        *(float4*)f1 = *(const float4*)&fwS[lidx(m0 + 1, kk * 4)];
#pragma unroll
        for (int j = 0; j < 4; j++) {
          s00 += ta0[j] * f0[j]; s01 += ta0[j] * f1[j];
          s10 += ta1[j] * f0[j]; s11 += ta1[j] * f1[j];
        }
      }
      pS[(h * 32 + n0) * 36 + m0] = s00;
      pS[(h * 32 + n0) * 36 + m0 + 1] = s01;
      pS[(h * 32 + n0 + 1) * 36 + m0] = s10;
      pS[(h * 32 + n0 + 1) * 36 + m0 + 1] = s11;
    }
    __syncthreads();
  }

  {
    const int r = t >> 2, sub = t & 3;
    const int base = r * 36 + sub * 8;
    float v0[4], v1[4];
    *(float4*)v0 = *(const float4*)&pS[base];
    *(float4*)v1 = *(const float4*)&pS[base + 4];
    float mx = fmaxf(fmaxf(fmaxf(v0[0], v0[1]), fmaxf(v0[2], v0[3])),
                     fmaxf(fmaxf(v1[0], v1[1]), fmaxf(v1[2], v1[3])));
    mx = fmaxf(mx, __shfl_xor(mx, 1, 64));
    mx = fmaxf(mx, __shfl_xor(mx, 2, 64));
    float sum = 0.f;
#pragma unroll
    for (int j = 0; j < 4; j++) { v0[j] = __expf(v0[j] - mx); sum += v0[j]; }
#pragma unroll
    for (int j = 0; j < 4; j++) { v1[j] = __expf(v1[j] - mx); sum += v1[j]; }
    sum += __shfl_xor(sum, 1, 64);
    sum += __shfl_xor(sum, 2, 64);
    const float inv = 1.0f / sum;
#pragma unroll
    for (int j = 0; j < 4; j++) { v0[j] *= inv; v1[j] *= inv; }
    *(float4*)&pS[base] = *(float4*)v0;
    *(float4*)&pS[base + 4] = *(float4*)v1;
  }
  __syncthreads();

  {
    float acc[2][8] = {};
    for (int dq = 0; dq < 64; dq += 4) {
      float fw0[4], fw1[4];
      *(float4*)fw0 = *(const float4*)&fwS[lidx(n0, dq)];
      *(float4*)fw1 = *(const float4*)&fwS[lidx(n0 + 1, dq)];
#pragma unroll
      for (int jj = 0; jj < 4; jj++) {
        float w8[8];
        *(float4*)&w8[0] = *(const float4*)(Wv + (dq + jj) * 128 + e0);
        *(float4*)&w8[4] = *(const float4*)(Wv + (dq + jj) * 128 + e0 + 4);
#pragma unroll
        for (int j = 0; j < 8; j++) {
          acc[0][j] += fw0[jj] * w8[j];
          acc[1][j] += fw1[jj] * w8[j];
        }
      }
    }
    *(float4*)&vS[n0 * 132 + e0] = *(float4*)&acc[0][0];
    *(float4*)&vS[n0 * 132 + e0 + 4] = *(float4*)&acc[0][4];
    *(float4*)&vS[(n0 + 1) * 132 + e0] = *(float4*)&acc[1][0];
    *(float4*)&vS[(n0 + 1) * 132 + e0 + 4] = *(float4*)&acc[1][4];
  }
  __syncthreads();

  {
    const int h2 = te >> 3;
    float pacc[2][8] = {};
    for (int m = 0; m < 32; m++) {
      float p0 = pS[(h2 * 32 + n0) * 36 + m];
      float p1 = pS[(h2 * 32 + n0 + 1) * 36 + m];
      float vr[8];
      *(float4*)&vr[0] = *(const float4*)&vS[m * 132 + e0];
      *(float4*)&vr[4] = *(const float4*)&vS[m * 132 + e0 + 4];
#pragma unroll
      for (int j = 0; j < 8; j++) {
        pacc[0][j] += p0 * vr[j];
        pacc[1][j] += p1 * vr[j];
      }
    }
    for (int dq = 0; dq < 64; dq += 4) {
      float fw0[4], fw1[4];
      *(float4*)fw0 = *(const float4*)&fwS[lidx(n0, dq)];
      *(float4*)fw1 = *(const float4*)&fwS[lidx(n0 + 1, dq)];
#pragma unroll
      for (int jj = 0; jj < 4; jj++) {
        float w8[8];
        *(float4*)&w8[0] = *(const float4*)(Wr + (dq + jj) * 128 + e0);
        *(float4*)&w8[4] = *(const float4*)(Wr + (dq + jj) * 128 + e0 + 4);
#pragma unroll
        for (int j = 0; j < 8; j++) {
          pacc[0][j] += fw0[jj] * w8[j];
          pacc[1][j] += fw1[jj] * w8[j];
        }
      }
    }
    __syncthreads();
    {
      float kh0 = khi[n0], kh1 = khi[n0 + 1];
      float ph[8];
#pragma unroll
      for (int j = 0; j < 8; j++)
        ph[j] = kh0 * fmaxf(pacc[0][j], 0.f) + kh1 * fmaxf(pacc[1][j], 0.f);
      *(float4*)&redH[tn * 132 + e0] = *(float4*)&ph[0];
      *(float4*)&redH[tn * 132 + e0 + 4] = *(float4*)&ph[4];
    }
  }
  *(float4*)&Kf[t * 4] = *(const float4*)(Kb + t * 4);
  __syncthreads();

  if (t < 128) {
    float s = 0.f;
#pragma unroll
    for (int k = 0; k < 16; k++) s += redH[k * 132 + t];
    out0[b * 256 + 128 + t] = s + bhi[t];
  }
  {
    const int c = t & 63, nq = t >> 6;
    float p = 0.f;
#pragma unroll
    for (int k = 0; k < 8; k++) {
      int nn = nq * 8 + k;
      float fv = fwS[lidx(nn, c)];
      float sv = ssq[b * 2048 + nn * 64 + c];
      p += (fv * fv - sv) * kfm[nn];
    }
    red1[nq * 68 + c] = p;
    float inner[8] = {};
    for (int r = 0; r < 32; r++) {
      float fr = fwS[lidx(r, c)];
#pragma unroll
      for (int l8 = 0; l8 < 8; l8++)
        inner[l8] += Kf[(nq * 8 + l8) * 32 + r] * fr;
    }
    float hmf = 0.f;
#pragma unroll
    for (int l8 = 0; l8 < 8; l8++)
      hmf += fwS[lidx(nq * 8 + l8, c)] * inner[l8];
    red1[(4 + nq) * 68 + c] = hmf;
  }
  __syncthreads();
  if (t < 64) {
    out0[b * 256 + t] = red1[t] + red1[68 + t] + red1[136 + t] + red1[204 + t] + bfm[t];
    float h2 = red1[272 + t] + red1[340 + t] + red1[408 + t] + red1[476 + t];
    out0[b * 256 + 64 + t] = 0.5f * h2 + bmf[t];
  }
}

// ---------------------------------------------------------------------------
extern "C" void kernel_launch(void* const* d_in, const int* in_sizes, int n_in,
                              void* d_out, int out_size, void* d_ws, size_t ws_size,
                              hipStream_t stream) {
  (void)in_sizes; (void)n_in; (void)out_size; (void)ws_size;
  const float* x     = (const float*)d_in[0];
  const float* W     = (const float*)d_in[1];
  const float* rinit = (const float*)d_in[2];
  const float* kfm   = (const float*)d_in[3];
  const float* bfm   = (const float*)d_in[4];
  const float* kmf   = (const float*)d_in[5];
  const float* bmf   = (const float*)d_in[6];
  const float* khi   = (const float*)d_in[7];
  const float* bhi   = (const float*)d_in[8];
  const float* Wq    = (const float*)d_in[9];
  const float* Wk    = (const float*)d_in[10];
  const float* Wv    = (const float*)d_in[11];
  const float* Wr    = (const float*)d_in[12];

  float* out0 = (float*)d_out;
  float* rs   = out0 + 1024 * 256;  // routing_score [B,32,64,1]

  float* ws   = (float*)d_ws;       // 24 MB
  float* Abuf = ws;                 // [2][64][64] = 8192 f
  float* Kbuf = ws + 8192;          // [32][32]    = 1024 f
  float* Qbuf = ws + 16384;         // [32][64][64] = 131072 f
  float* fwv  = ws + 2097152;       // [B,32,64]
  float* ssq  = ws + 2 * 2097152;   // [B,32,64]

  k_prep2<<<41, 256, 0, stream>>>(W, Wq, Wk, kmf, Qbuf, Abuf, Kbuf);
  k_route3<<<512, 512, 0, stream>>>(x, W, rinit, Qbuf, rs, fwv);
  k_ih<<<1024, 256, 0, stream>>>(x, W, rs, ssq);
  k_attn<<<1024, 256, 0, stream>>>(fwv, ssq, Abuf, Kbuf, Wv, Wr,
                                   kfm, bfm, bmf, khi, bhi, out0);
}

// Round 3
// 260.064 us; speedup vs baseline: 1.0504x; 1.0081x over previous
//
#include <hip/hip_runtime.h>

// CapsuleLayer fused pipeline, round 10.
//  - R9 POST-MORTEM: SQ_LDS_BANK_CONFLICT bit-identical (9437184) across R8/R9
//    -> conflicts come from an untouched phase. Per-8-lane phase analysis:
//    the delta-b phase's xs read (r = tlo*4+i, col uniform) puts 8 lanes on
//    only 2 bank-quads (r&7 has 2 values) = 4-way conflict on the hottest
//    LDS read (192 b128/thread). Everything else was already conflict-free.
//  - R10: swizzle gains row bits 2-3: swz = ((c>>2) ^ r ^ (r>>2)) & 15.
//    Enumerated: delta-b read now hits all 8 quads; all other phases stay
//    conflict-free/2-way. Single-function change, no arithmetic change.
//  - k_prep2 / k_ih / k_attn unchanged (known-good).
//  - NO cooperative launches (R6 lesson: harness graph capture fails).

#define EPS_SQ 1e-7f

typedef __attribute__((ext_vector_type(8))) short bf16x8;
typedef __attribute__((ext_vector_type(4))) float floatx4;

__device__ __forceinline__ int lidx(int r, int c) {
  // 64-col fp32 tile, row stride 68 dwords, quad-swizzle (legacy kernels)
  return r * 68 + ((((c >> 2) ^ (r >> 2)) & 15) << 2) + (c & 3);
}
__device__ __forceinline__ int lidx64(int r, int c) {
  // unpadded 64-col fp32 tile, XOR swizzle at float4 granularity.
  // R10: include r>>2 so rows stepping by 4 (delta-b read) rotate bank-quads.
  return r * 64 + ((((c >> 2) ^ r ^ (r >> 2)) & 15) << 2) + (c & 3);
}
__device__ __forceinline__ unsigned short f2bf(float f) {
  unsigned u = __float_as_uint(f);
  u += 0x7FFFu + ((u >> 16) & 1u);   // RNE
  return (unsigned short)(u >> 16);
}

// ---------------------------------------------------------------------------
// k_prep2: bid<32: Q_n = M_n.M_n^T ; bid 32..39: A_h = Wq_h.Wk_h^T ;
//          bid 40: symmetric pair matrix K from kmf.  (unchanged)
// ---------------------------------------------------------------------------
__global__ __launch_bounds__(256) void k_prep2(
    const float* __restrict__ W, const float* __restrict__ Wq,
    const float* __restrict__ Wk, const float* __restrict__ kmf,
    float* __restrict__ Qb, float* __restrict__ Ab, float* __restrict__ Kb)
{
  const int t = threadIdx.x;
  if (blockIdx.x < 32) {
    __shared__ __align__(16) float Mn[64 * 68];
    const int n = blockIdx.x;
#pragma unroll
    for (int k = 0; k < 4; k++) {
      int lin = t + 256 * k; int d = lin >> 4; int c0 = (lin & 15) << 2;
      *(float4*)&Mn[lidx(d, c0)] = *(const float4*)(W + d * 2048 + n * 64 + c0);
    }
    __syncthreads();
    const int d1 = (t >> 4) * 4, d2 = (t & 15) * 4;
    float acc[4][4] = {};
    for (int cq = 0; cq < 64; cq += 4) {
      float m1[4][4], m2[4][4];
#pragma unroll
      for (int i = 0; i < 4; i++) *(float4*)m1[i] = *(const float4*)&Mn[lidx(d1 + i, cq)];
#pragma unroll
      for (int j = 0; j < 4; j++) *(float4*)m2[j] = *(const float4*)&Mn[lidx(d2 + j, cq)];
#pragma unroll
      for (int i = 0; i < 4; i++)
#pragma unroll
        for (int j = 0; j < 4; j++) {
          float s = 0.f;
#pragma unroll
          for (int k = 0; k < 4; k++) s += m1[i][k] * m2[j][k];
          acc[i][j] += s;
        }
    }
#pragma unroll
    for (int i = 0; i < 4; i++)
      *(float4*)(Qb + n * 4096 + (d1 + i) * 64 + d2) = *(float4*)acc[i];
  } else if (blockIdx.x < 40) {
    __shared__ __align__(16) float wkS[64 * 68];
    __shared__ __align__(16) float wqS[16 * 68];
    const int hb = blockIdx.x - 32;
    const int h = hb & 1, rg = hb >> 1;
#pragma unroll
    for (int k = 0; k < 4; k++) {
      int lin = t + 256 * k; int dp = lin >> 4; int e0 = (lin & 15) << 2;
      *(float4*)&wkS[lidx(dp, e0)] = *(const float4*)(Wk + dp * 128 + h * 64 + e0);
    }
    {
      int dl = t >> 4, e0 = (t & 15) << 2;
      *(float4*)&wqS[lidx(dl, e0)] = *(const float4*)(Wq + (rg * 16 + dl) * 128 + h * 64 + e0);
    }
    __syncthreads();
    const int dl = t >> 4, dp0 = (t & 15) << 2;
    float acc[4] = {};
    for (int e = 0; e < 64; e += 4) {
      float q4[4];
      *(float4*)q4 = *(const float4*)&wqS[lidx(dl, e)];
#pragma unroll
      for (int c = 0; c < 4; c++) {
        float mr[4];
        *(float4*)mr = *(const float4*)&wkS[lidx(dp0 + c, e)];
        acc[c] += q4[0] * mr[0] + q4[1] * mr[1] + q4[2] * mr[2] + q4[3] * mr[3];
      }
    }
    *(float4*)(Ab + h * 4096 + (rg * 16 + dl) * 64 + dp0) = *(float4*)acc;
  } else {
    __shared__ float Ks[1024];
    *(float4*)&Ks[t * 4] = make_float4(0.f, 0.f, 0.f, 0.f);
    __syncthreads();
    if (t < 248) {
#pragma unroll
      for (int j = 0; j < 2; j++) {
        int p = t * 2 + j;
        if (p < 496) {
          int l = 0, rem = p;
          while (rem >= 31 - l) { rem -= 31 - l; ++l; }
          int r = l + 1 + rem;
          float v = kmf[p];
          Ks[l * 32 + r] = v;
          Ks[r * 32 + l] = v;
        }
      }
    }
    __syncthreads();
    *(float4*)&Kb[t * 4] = *(const float4*)&Ks[t * 4];
  }
}

// ---------------------------------------------------------------------------
// k_route3: routing for TWO b's per 512-thread block.
//   Per-b phases (softmax, xc, delta-b): lower 4 waves = b0, upper = b1.
//   Cross-b phases (ow: xc.Q with Q streamed; fwv: xc.W): every thread
//   loads each Q/W float4 once and uses it for both b's.
//   LDS per b: xs 16K | bS 8K | cOw 8K (cS aliased with owS) | xcS 8K
//   = 40 KB; 80 KB/block -> 2 blocks/CU.
// ---------------------------------------------------------------------------
__global__ __launch_bounds__(512, 4) void k_route3(
    const float* __restrict__ x, const float* __restrict__ W,
    const float* __restrict__ rinit, const float* __restrict__ Qb,
    float* __restrict__ rs, float* __restrict__ fwv)
{
  __shared__ __align__(16) float smem[2 * 10240];   // 81920 B exactly

  const int t = threadIdx.x;
  const int tb = t >> 8, tt = t & 255;
  const int b = blockIdx.x * 2 + tb;

  float* xs  = smem + tb * 10240;          // 64x64 (swizzled)
  float* bS  = smem + tb * 10240 + 4096;   // 32x64 logits (persistent)
  float* cOw = smem + tb * 10240 + 6144;   // 32x64 cS aliased with owS
  float* xcS = smem + tb * 10240 + 8192;   // 32x64

  // cross-b views for ow / fwv phases
  float* xc0 = smem + 8192;
  float* xc1 = smem + 10240 + 8192;
  float* ow0 = smem + 6144;
  float* ow1 = smem + 10240 + 6144;

  // ---- stage x[b] and rinit ----------------------------------------------
#pragma unroll
  for (int k = 0; k < 4; k++) {
    int lin = tt + 256 * k; int f = lin >> 4; int d0 = (lin & 15) << 2;
    *(float4*)&xs[lidx64(f, d0)] = *(const float4*)(x + b * 4096 + f * 64 + d0);
  }
#pragma unroll
  for (int k = 0; k < 2; k++) {
    int lin = tt + 256 * k; int n = lin >> 4; int f0 = (lin & 15) << 2;
    *(float4*)&bS[lidx64(n, f0)] = *(const float4*)(rinit + n * 64 + f0);
  }
  __syncthreads();

  const int tn = tt >> 4, tlo = tt & 15;
  const int nq = t >> 4, sub = t & 15;     // cross-b mapping: 32 n x 4 cols

  for (int it = 0; it < 4; it++) {
    // ---- cS = softmax over n per f column (per-b) -------------------------
    {
      const int nl = tt & 31, fg = tt >> 5;   // fg 0..7
#pragma unroll
      for (int qq = 0; qq < 2; qq++) {
        const int f0 = (fg * 2 + qq) * 4;
        float v[4];
        *(float4*)v = *(const float4*)&bS[lidx64(nl, f0)];
        float e[4];
#pragma unroll
        for (int j = 0; j < 4; j++) {
          float m = v[j];
          m = fmaxf(m, __shfl_xor(m, 16, 64));
          m = fmaxf(m, __shfl_xor(m, 8, 64));
          m = fmaxf(m, __shfl_xor(m, 4, 64));
          m = fmaxf(m, __shfl_xor(m, 2, 64));
          m = fmaxf(m, __shfl_xor(m, 1, 64));
          e[j] = __expf(v[j] - m);
          float s = e[j];
          s += __shfl_xor(s, 16, 64);
          s += __shfl_xor(s, 8, 64);
          s += __shfl_xor(s, 4, 64);
          s += __shfl_xor(s, 2, 64);
          s += __shfl_xor(s, 1, 64);
          e[j] /= s;
        }
        *(float4*)&cOw[lidx64(nl, f0)] = *(float4*)e;
      }
    }
    __syncthreads();
    if (it == 3) {
#pragma unroll
      for (int k = 0; k < 2; k++) {
        int lin = tt + 256 * k;              // 0..511
        int n = lin >> 4, fq = lin & 15;
        float4 v = *(const float4*)&cOw[lidx64(n, fq * 4)];
        *(float4*)(rs + b * 2048 + n * 64 + fq * 4) = v;
      }
    }
    // ---- xcS = cS . xs (per-b) -------------------------------------------
    {
      const int n0 = tn * 2, d0 = tlo * 4;
      float acc[2][4] = {{0, 0, 0, 0}, {0, 0, 0, 0}};
      for (int fq = 0; fq < 16; fq++) {
        float c0[4], c1[4];
        *(float4*)c0 = *(const float4*)&cOw[lidx64(n0, fq * 4)];
        *(float4*)c1 = *(const float4*)&cOw[lidx64(n0 + 1, fq * 4)];
#pragma unroll
        for (int j = 0; j < 4; j++) {
          float xr[4];
          *(float4*)xr = *(const float4*)&xs[lidx64(fq * 4 + j, d0)];
#pragma unroll
          for (int i = 0; i < 4; i++) {
            acc[0][i] += c0[j] * xr[i];
            acc[1][i] += c1[j] * xr[i];
          }
        }
      }
      *(float4*)&xcS[lidx64(n0, d0)] = *(float4*)acc[0];
      *(float4*)&xcS[lidx64(n0 + 1, d0)] = *(float4*)acc[1];
    }
    __syncthreads();
    if (it == 3) break;

    // ---- ow = scale * (xc . Q_n): CROSS-B, Q streamed once ----------------
    {
      const float* Qn = Qb + nq * 4096 + sub * 4;
      float y0[4] = {}, y1[4] = {};
#pragma unroll 4
      for (int dq = 0; dq < 16; dq++) {
        float xv0[4], xv1[4];
        *(float4*)xv0 = *(const float4*)&xc0[lidx64(nq, dq * 4)];
        *(float4*)xv1 = *(const float4*)&xc1[lidx64(nq, dq * 4)];
#pragma unroll
        for (int j = 0; j < 4; j++) {
          float4 q = *(const float4*)(Qn + (dq * 4 + j) * 64);
          y0[0] += xv0[j] * q.x; y0[1] += xv0[j] * q.y;
          y0[2] += xv0[j] * q.z; y0[3] += xv0[j] * q.w;
          y1[0] += xv1[j] * q.x; y1[1] += xv1[j] * q.y;
          y1[2] += xv1[j] * q.z; y1[3] += xv1[j] * q.w;
        }
      }
      float xa0[4], xa1[4];
      *(float4*)xa0 = *(const float4*)&xc0[lidx64(nq, sub * 4)];
      *(float4*)xa1 = *(const float4*)&xc1[lidx64(nq, sub * 4)];
      float ps0 = y0[0] * xa0[0] + y0[1] * xa0[1] + y0[2] * xa0[2] + y0[3] * xa0[3];
      float ps1 = y1[0] * xa1[0] + y1[1] * xa1[1] + y1[2] * xa1[2] + y1[3] * xa1[3];
      ps0 += __shfl_xor(ps0, 1, 64); ps0 += __shfl_xor(ps0, 2, 64);
      ps0 += __shfl_xor(ps0, 4, 64); ps0 += __shfl_xor(ps0, 8, 64);
      ps1 += __shfl_xor(ps1, 1, 64); ps1 += __shfl_xor(ps1, 2, 64);
      ps1 += __shfl_xor(ps1, 4, 64); ps1 += __shfl_xor(ps1, 8, 64);
      const float ss0 = ps0 + EPS_SQ, ss1 = ps1 + EPS_SQ;
      const float sc0 = sqrtf(ss0) / (0.5f + ss0);
      const float sc1 = sqrtf(ss1) / (0.5f + ss1);
      float o0[4] = {y0[0] * sc0, y0[1] * sc0, y0[2] * sc0, y0[3] * sc0};
      float o1[4] = {y1[0] * sc1, y1[1] * sc1, y1[2] * sc1, y1[3] * sc1};
      *(float4*)&ow0[lidx64(nq, sub * 4)] = *(float4*)o0;
      *(float4*)&ow1[lidx64(nq, sub * 4)] = *(float4*)o1;
    }
    __syncthreads();

    // ---- bS += xs . owS^T (per-b) ----------------------------------------
    {
      const int n0 = tn * 2, f0 = tlo * 4;
      float acc[2][4] = {{0, 0, 0, 0}, {0, 0, 0, 0}};
      for (int dq = 0; dq < 64; dq += 4) {
        float o[2][4];
        *(float4*)o[0] = *(const float4*)&cOw[lidx64(n0, dq)];
        *(float4*)o[1] = *(const float4*)&cOw[lidx64(n0 + 1, dq)];
#pragma unroll
        for (int i = 0; i < 4; i++) {
          float xr[4];
          *(float4*)xr = *(const float4*)&xs[lidx64(f0 + i, dq)];
#pragma unroll
          for (int k = 0; k < 4; k++) {
            acc[0][i] += o[0][k] * xr[k];
            acc[1][i] += o[1][k] * xr[k];
          }
        }
      }
#pragma unroll
      for (int j = 0; j < 2; j++) {
        float tmp[4];
        *(float4*)tmp = *(const float4*)&bS[lidx64(n0 + j, f0)];
#pragma unroll
        for (int i = 0; i < 4; i++) tmp[i] += acc[j][i];
        *(float4*)&bS[lidx64(n0 + j, f0)] = *(float4*)tmp;
      }
    }
    __syncthreads();
  }

  // ---- fwv = xcS . W: CROSS-B, W streamed once ----------------------------
  {
    const float* Wn = W + nq * 64 + sub * 4;
    float a0[4] = {}, a1[4] = {};
#pragma unroll 4
    for (int dq = 0; dq < 16; dq++) {
      float xv0[4], xv1[4];
      *(float4*)xv0 = *(const float4*)&xc0[lidx64(nq, dq * 4)];
      *(float4*)xv1 = *(const float4*)&xc1[lidx64(nq, dq * 4)];
#pragma unroll
      for (int j = 0; j < 4; j++) {
        float4 w = *(const float4*)(Wn + (dq * 4 + j) * 2048);
        a0[0] += xv0[j] * w.x; a0[1] += xv0[j] * w.y;
        a0[2] += xv0[j] * w.z; a0[3] += xv0[j] * w.w;
        a1[0] += xv1[j] * w.x; a1[1] += xv1[j] * w.y;
        a1[2] += xv1[j] * w.z; a1[3] += xv1[j] * w.w;
      }
    }
    const int b0g = blockIdx.x * 2;
    *(float4*)(fwv + b0g * 2048 + nq * 64 + sub * 4) = *(float4*)a0;
    *(float4*)(fwv + (b0g + 1) * 2048 + nq * 64 + sub * 4) = *(float4*)a1;
  }
}

// ---------------------------------------------------------------------------
// k_ih: ssq via bf16 MFMA. Block = 4 b's x 8 n's, grid 1024. (unchanged)
// ---------------------------------------------------------------------------
__global__ __launch_bounds__(256) void k_ih(
    const float* __restrict__ x, const float* __restrict__ W,
    const float* __restrict__ rs, float* __restrict__ ssq)
{
  __shared__ __align__(16) unsigned short xB[4 * 64 * 64];   // 32768 B
  __shared__ __align__(16) unsigned short wB[2 * 64 * 64];   // 16384 B
  __shared__ unsigned short cF2[4 * 8 * 64];                 // 4096 B
  const int n_oct = (blockIdx.x & 3) << 3, b0 = (blockIdx.x >> 2) * 4;
  const int t = threadIdx.x, w = t >> 6, lane = t & 63;

#pragma unroll
  for (int k = 0; k < 16; k++) {
    int ch = t + 256 * k;
    int bb = ch >> 10, rem = ch & 1023;
    int f = rem >> 4, fq = rem & 15;
    int dg = fq >> 1, half = fq & 1;
    float4 v = *(const float4*)(x + ((b0 + bb) * 64 + f) * 64 + fq * 4);
    unsigned p0 = f2bf(v.x) | ((unsigned)f2bf(v.y) << 16);
    unsigned p1 = f2bf(v.z) | ((unsigned)f2bf(v.w) << 16);
    *(uint2*)&xB[bb * 4096 + f * 64 + ((dg ^ (f & 7)) << 3) + half * 4] =
        make_uint2(p0, p1);
  }
#pragma unroll
  for (int nn = 0; nn < 8; nn++) {
    float v = rs[(b0 + w) * 2048 + (n_oct + nn) * 64 + lane];
    cF2[(w * 8 + nn) * 64 + lane] = f2bf(v * v);
  }
  __syncthreads();

  const int m = lane & 15, q = lane >> 4, ms = m & 7;
  bf16x8 a[4][2];
#pragma unroll
  for (int mi = 0; mi < 4; mi++) {
    const unsigned short* bp = xB + w * 4096 + (mi * 16 + m) * 64;
#pragma unroll
    for (int kk = 0; kk < 2; kk++)
      a[mi][kk] = *(const bf16x8*)&bp[((kk * 4 + q) ^ ms) << 3];
  }

  for (int np = 0; np < 4; np++) {
    const int n0 = n_oct + np * 2;
    __syncthreads();
    {
      int dd = t >> 2, cq = t & 3;
      int dg = dd >> 3, dl = dd & 7;
#pragma unroll
      for (int nn = 0; nn < 2; nn++) {
        const float* wp = W + dd * 2048 + (n0 + nn) * 64 + cq * 16;
        unsigned short* base = wB + nn * 4096;
#pragma unroll
        for (int i4 = 0; i4 < 4; i4++) {
          float4 v = *(const float4*)(wp + i4 * 4);
          float vv[4] = {v.x, v.y, v.z, v.w};
#pragma unroll
          for (int j = 0; j < 4; j++) {
            int c = cq * 16 + i4 * 4 + j;
            base[c * 64 + ((dg ^ (c & 7)) << 3) + dl] = f2bf(vv[j]);
          }
        }
      }
    }
    __syncthreads();
#pragma unroll
    for (int nn = 0; nn < 2; nn++) {
      bf16x8 bf[4][2];
#pragma unroll
      for (int ci = 0; ci < 4; ci++) {
        const unsigned short* bp = wB + nn * 4096 + (ci * 16 + m) * 64;
#pragma unroll
        for (int kk = 0; kk < 2; kk++)
          bf[ci][kk] = *(const bf16x8*)&bp[((kk * 4 + q) ^ ms) << 3];
      }
      float ps[4] = {0.f, 0.f, 0.f, 0.f};
      const unsigned short* cf = cF2 + (w * 8 + np * 2 + nn) * 64 + q * 4;
#pragma unroll
      for (int mi = 0; mi < 4; mi++) {
        float cfv[4];
#pragma unroll
        for (int r = 0; r < 4; r++)
          cfv[r] = __uint_as_float((unsigned)cf[mi * 16 + r] << 16);
#pragma unroll
        for (int ci = 0; ci < 4; ci++) {
          floatx4 c0 = {0.f, 0.f, 0.f, 0.f};
          c0 = __builtin_amdgcn_mfma_f32_16x16x32_bf16(a[mi][0], bf[ci][0], c0, 0, 0, 0);
          c0 = __builtin_amdgcn_mfma_f32_16x16x32_bf16(a[mi][1], bf[ci][1], c0, 0, 0, 0);
#pragma unroll
          for (int r = 0; r < 4; r++) { float tv = c0[r]; ps[ci] += cfv[r] * tv * tv; }
        }
      }
#pragma unroll
      for (int ci = 0; ci < 4; ci++) {
        ps[ci] += __shfl_xor(ps[ci], 16, 64);
        ps[ci] += __shfl_xor(ps[ci], 32, 64);
      }
      if (q == 0) {
#pragma unroll
        for (int ci = 0; ci < 4; ci++)
          ssq[(b0 + w) * 2048 + (n0 + nn) * 64 + ci * 16 + m] = ps[ci];
      }
    }
  }
}

// ---------------------------------------------------------------------------
// k_attn: per-b fused attention + FM + MF + high_int. (unchanged)
// ---------------------------------------------------------------------------
__global__ __launch_bounds__(256) void k_attn(
    const float* __restrict__ fwv, const float* __restrict__ ssq,
    const float* __restrict__ Ab, const float* __restrict__ Kb,
    const float* __restrict__ Wv, const float* __restrict__ Wr,
    const float* __restrict__ kfm, const float* __restrict__ bfm,
    const float* __restrict__ bmf, const float* __restrict__ khi,
    const float* __restrict__ bhi, float* __restrict__ out0)
{
  __shared__ __align__(16) float smem[8832];   // 35328 B
  float* fwS  = smem;               // 32x68 (2176 f)
  float* pS   = smem + 2176;        // 64x36 (2304 f)
  float* bufA = smem + 4480;        // 32x68 (2176 f)
  float* tS   = smem + 6656;        // 32x68 (2176 f)
  float* vS   = smem + 4480;        // 32x132 (4224 f) (alias)
  float* redH = smem + 2176;        // 16x132 (alias of pS)
  float* Kf   = smem + 4480;        // 32x32 (alias, post-vS)
  float* red1 = smem + 5504;        // 8x68

  const int b = blockIdx.x, t = threadIdx.x;
  const int tn = t >> 4, te = t & 15;
  const int n0 = tn * 2, e0 = te * 8, d0 = te * 4;

#pragma unroll
  for (int k = 0; k < 2; k++) {
    int lin = t + 256 * k; int nn = lin >> 4; int c0 = (lin & 15) << 2;
    *(float4*)&fwS[lidx(nn, c0)] = *(const float4*)(fwv + b * 2048 + nn * 64 + c0);
  }
  __syncthreads();

  for (int h = 0; h < 2; h++) {
    float tacc[2][4] = {};
    for (int half = 0; half < 2; half++) {
#pragma unroll
      for (int k = 0; k < 2; k++) {
        int lin = t + 256 * k; int d = lin >> 4; int c0 = (lin & 15) << 2;
        *(float4*)&bufA[lidx(d, c0)] =
            *(const float4*)(Ab + h * 4096 + (half * 32 + d) * 64 + c0);
      }
      __syncthreads();
      for (int dq = 0; dq < 32; dq += 4) {
        float fw0[4], fw1[4];
        *(float4*)fw0 = *(const float4*)&fwS[lidx(n0, half * 32 + dq)];
        *(float4*)fw1 = *(const float4*)&fwS[lidx(n0 + 1, half * 32 + dq)];
#pragma unroll
        for (int j = 0; j < 4; j++) {
          float mr[4];
          *(float4*)mr = *(const float4*)&bufA[lidx(dq + j, d0)];
#pragma unroll
          for (int c = 0; c < 4; c++) {
            tacc[0][c] += fw0[j] * mr[c];
            tacc[1][c] += fw1[j] * mr[c];
          }
        }
      }
      __syncthreads();
    }
    *(float4*)&tS[lidx(n0, d0)] = *(float4*)tacc[0];
    *(float4*)&tS[lidx(n0 + 1, d0)] = *(float4*)tacc[1];
    __syncthreads();
    {
      const int m0 = te * 2;
      float s00 = 0.f, s01 = 0.f, s10 = 0.f, s11 = 0.f;
      for (int kk = 0; kk < 16; kk++) {
        float ta0[4], ta1[4], f0[4], f1[4];
        *(float4*)ta0 = *(const float4*)&tS[lidx(n0, kk * 4)];
        *(float4*)ta1 = *(const float4*)&tS[lidx(n0 + 1, kk * 4)];
        *(float4*)f0 = *(const float4*)&fwS[lidx(m0, kk * 4)];
        *(float4*)f1 = *(const float4*)&fwS[lidx(m0 + 1, kk * 4)];
#pragma unroll
        for (int j = 0; j < 4; j++) {
          s00 += ta0[j] * f0[j]; s01 += ta0[j] * f1[j];
          s10 += ta1[j] * f0[j]; s11 += ta1[j] * f1[j];
        }
      }
      pS[(h * 32 + n0) * 36 + m0] = s00;
      pS[(h * 32 + n0) * 36 + m0 + 1] = s01;
      pS[(h * 32 + n0 + 1) * 36 + m0] = s10;
      pS[(h * 32 + n0 + 1) * 36 + m0 + 1] = s11;
    }
    __syncthreads();
  }

  {
    const int r = t >> 2, sub = t & 3;
    const int base = r * 36 + sub * 8;
    float v0[4], v1[4];
    *(float4*)v0 = *(const float4*)&pS[base];
    *(float4*)v1 = *(const float4*)&pS[base + 4];
    float mx = fmaxf(fmaxf(fmaxf(v0[0], v0[1]), fmaxf(v0[2], v0[3])),
                     fmaxf(fmaxf(v1[0], v1[1]), fmaxf(v1[2], v1[3])));
    mx = fmaxf(mx, __shfl_xor(mx, 1, 64));
    mx = fmaxf(mx, __shfl_xor(mx, 2, 64));
    float sum = 0.f;
#pragma unroll
    for (int j = 0; j < 4; j++) { v0[j] = __expf(v0[j] - mx); sum += v0[j]; }
#pragma unroll
    for (int j = 0; j < 4; j++) { v1[j] = __expf(v1[j] - mx); sum += v1[j]; }
    sum += __shfl_xor(sum, 1, 64);
    sum += __shfl_xor(sum, 2, 64);
    const float inv = 1.0f / sum;
#pragma unroll
    for (int j = 0; j < 4; j++) { v0[j] *= inv; v1[j] *= inv; }
    *(float4*)&pS[base] = *(float4*)v0;
    *(float4*)&pS[base + 4] = *(float4*)v1;
  }
  __syncthreads();

  {
    float acc[2][8] = {};
    for (int dq = 0; dq < 64; dq += 4) {
      float fw0[4], fw1[4];
      *(float4*)fw0 = *(const float4*)&fwS[lidx(n0, dq)];
      *(float4*)fw1 = *(const float4*)&fwS[lidx(n0 + 1, dq)];
#pragma unroll
      for (int jj = 0; jj < 4; jj++) {
        float w8[8];
        *(float4*)&w8[0] = *(const float4*)(Wv + (dq + jj) * 128 + e0);
        *(float4*)&w8[4] = *(const float4*)(Wv + (dq + jj) * 128 + e0 + 4);
#pragma unroll
        for (int j = 0; j < 8; j++) {
          acc[0][j] += fw0[jj] * w8[j];
          acc[1][j] += fw1[jj] * w8[j];
        }
      }
    }
    *(float4*)&vS[n0 * 132 + e0] = *(float4*)&acc[0][0];
    *(float4*)&vS[n0 * 132 + e0 + 4] = *(float4*)&acc[0][4];
    *(float4*)&vS[(n0 + 1) * 132 + e0] = *(float4*)&acc[1][0];
    *(float4*)&vS[(n0 + 1) * 132 + e0 + 4] = *(float4*)&acc[1][4];
  }
  __syncthreads();

  {
    const int h2 = te >> 3;
    float pacc[2][8] = {};
    for (int m = 0; m < 32; m++) {
      float p0 = pS[(h2 * 32 + n0) * 36 + m];
      float p1 = pS[(h2 * 32 + n0 + 1) * 36 + m];
      float vr[8];
      *(float4*)&vr[0] = *(const float4*)&vS[m * 132 + e0];
      *(float4*)&vr[4] = *(const float4*)&vS[m * 132 + e0 + 4];
#pragma unroll
      for (int j = 0; j < 8; j++) {
        pacc[0][j] += p0 * vr[j];
        pacc[1][j] += p1 * vr[j];
      }
    }
    for (int dq = 0; dq < 64; dq += 4) {
      float fw0[4], fw1[4];
      *(float4*)fw0 = *(const float4*)&fwS[lidx(n0, dq)];
      *(float4*)fw1 = *(const float4*)&fwS[lidx(n0 + 1, dq)];
#pragma unroll
      for (int jj = 0; jj < 4; jj++) {
        float w8[8];
        *(float4*)&w8[0] = *(const float4*)(Wr + (dq + jj) * 128 + e0);
        *(float4*)&w8[4] = *(const float4*)(Wr + (dq + jj) * 128 + e0 + 4);
#pragma unroll
        for (int j = 0; j < 8; j++) {
          pacc[0][j] += fw0[jj] * w8[j];
          pacc[1][j] += fw1[jj] * w8[j];
        }
      }
    }
    __syncthreads();
    {
      float kh0 = khi[n0], kh1 = khi[n0 + 1];
      float ph[8];
#pragma unroll
      for (int j = 0; j < 8; j++)
        ph[j] = kh0 * fmaxf(pacc[0][j], 0.f) + kh1 * fmaxf(pacc[1][j], 0.f);
      *(float4*)&redH[tn * 132 + e0] = *(float4*)&ph[0];
      *(float4*)&redH[tn * 132 + e0 + 4] = *(float4*)&ph[4];
    }
  }
  *(float4*)&Kf[t * 4] = *(const float4*)(Kb + t * 4);
  __syncthreads();

  if (t < 128) {
    float s = 0.f;
#pragma unroll
    for (int k = 0; k < 16; k++) s += redH[k * 132 + t];
    out0[b * 256 + 128 + t] = s + bhi[t];
  }
  {
    const int c = t & 63, nq = t >> 6;
    float p = 0.f;
#pragma unroll
    for (int k = 0; k < 8; k++) {
      int nn = nq * 8 + k;
      float fv = fwS[lidx(nn, c)];
      float sv = ssq[b * 2048 + nn * 64 + c];
      p += (fv * fv - sv) * kfm[nn];
    }
    red1[nq * 68 + c] = p;
    float inner[8] = {};
    for (int r = 0; r < 32; r++) {
      float fr = fwS[lidx(r, c)];
#pragma unroll
      for (int l8 = 0; l8 < 8; l8++)
        inner[l8] += Kf[(nq * 8 + l8) * 32 + r] * fr;
    }
    float hmf = 0.f;
#pragma unroll
    for (int l8 = 0; l8 < 8; l8++)
      hmf += fwS[lidx(nq * 8 + l8, c)] * inner[l8];
    red1[(4 + nq) * 68 + c] = hmf;
  }
  __syncthreads();
  if (t < 64) {
    out0[b * 256 + t] = red1[t] + red1[68 + t] + red1[136 + t] + red1[204 + t] + bfm[t];
    float h2 = red1[272 + t] + red1[340 + t] + red1[408 + t] + red1[476 + t];
    out0[b * 256 + 64 + t] = 0.5f * h2 + bmf[t];
  }
}

// ---------------------------------------------------------------------------
extern "C" void kernel_launch(void* const* d_in, const int* in_sizes, int n_in,
                              void* d_out, int out_size, void* d_ws, size_t ws_size,
                              hipStream_t stream) {
  (void)in_sizes; (void)n_in; (void)out_size; (void)ws_size;
  const float* x     = (const float*)d_in[0];
  const float* W     = (const float*)d_in[1];
  const float* rinit = (const float*)d_in[2];
  const float* kfm   = (const float*)d_in[3];
  const float* bfm   = (const float*)d_in[4];
  const float* kmf   = (const float*)d_in[5];
  const float* bmf   = (const float*)d_in[6];
  const float* khi   = (const float*)d_in[7];
  const float* bhi   = (const float*)d_in[8];
  const float* Wq    = (const float*)d_in[9];
  const float* Wk    = (const float*)d_in[10];
  const float* Wv    = (const float*)d_in[11];
  const float* Wr    = (const float*)d_in[12];

  float* out0 = (float*)d_out;
  float* rs   = out0 + 1024 * 256;  // routing_score [B,32,64,1]

  float* ws   = (float*)d_ws;       // 24 MB
  float* Abuf = ws;                 // [2][64][64] = 8192 f
  float* Kbuf = ws + 8192;          // [32][32]    = 1024 f
  float* Qbuf = ws + 16384;         // [32][64][64] = 131072 f
  float* fwv  = ws + 2097152;       // [B,32,64]
  float* ssq  = ws + 2 * 2097152;   // [B,32,64]

  k_prep2<<<41, 256, 0, stream>>>(W, Wq, Wk, kmf, Qbuf, Abuf, Kbuf);
  k_route3<<<512, 512, 0, stream>>>(x, W, rinit, Qbuf, rs, fwv);
  k_ih<<<1024, 256, 0, stream>>>(x, W, rs, ssq);
  k_attn<<<1024, 256, 0, stream>>>(fwv, ssq, Abuf, Kbuf, Wv, Wr,
                                   kfm, bfm, bmf, khi, bhi, out0);
}